// Round 12
// baseline (227.778 us; speedup 1.0000x reference)
//
#include <hip/hip_runtime.h>
#include <cstdint>
#include <cstddef>

#define NEG_SLOPE 0.2f
#define LOG2E 1.44269504088896f
#define NREP 64

typedef __attribute__((ext_vector_type(8))) short bf16x8;
typedef __attribute__((ext_vector_type(4))) float f32x4;
typedef __attribute__((ext_vector_type(2))) float f32x2;

__device__ __forceinline__ ushort f2b(float f) {   // fp32 -> bf16 RNE
  unsigned u = __float_as_uint(f);
  return (ushort)((u + 0x7FFFu + ((u >> 16) & 1)) >> 16);
}
__device__ __forceinline__ float fexp2(float x) {
#if __has_builtin(__builtin_amdgcn_exp2f)
  return __builtin_amdgcn_exp2f(x);
#else
  return __exp2f(x);
#endif
}
__device__ __forceinline__ int lbound(const int* __restrict__ a, int n, int key) {
  int lo = 0, hi = n;
  while (lo < hi) { int m = (lo + hi) >> 1; if (a[m] < key) lo = m + 1; else hi = m; }
  return lo;
}

// ---------------- setup: pack W1+W2 -> bf16 [K/8][N][8]; zero hist & pp ------
// grid: 128 blocks x 256 (i < 32768)
__global__ __launch_bounds__(256) void setup_k(const float* __restrict__ W1,
                                               ushort* __restrict__ Bp1,
                                               const float* __restrict__ W2,
                                               ushort* __restrict__ Bp2,
                                               int* __restrict__ hist,
                                               float* __restrict__ pp, int n) {
  int i = blockIdx.x * 256 + threadIdx.x;
  {
    int k = i >> 8, c = i & 255;                  // W1: K=128, N=256
    Bp1[(((size_t)(k >> 3) * 256 + c) << 3) + (k & 7)] = f2b(W1[i]);
  }
  {
    int k = i >> 7, c = i & 127;                  // W2: K=256, N=128
    Bp2[(((size_t)(k >> 3) * 128 + c) << 3) + (k & 7)] = f2b(W2[i]);
  }
  if (i < n) hist[i] = 0;
  int i2 = i + 32768;
  if (i2 < n) hist[i2] = 0;
  pp[i] = 0.f;                                    // pp = 64*8*128 = 65536
  pp[i + 32768] = 0.f;
}

// ---------------- shared GEMM+attn body (bf16 MFMA, fp8 C, exp2-domain attn) -
template<int N, int K, int C, int H, bool AF32>
__device__ __forceinline__ void gemm_attn_body(const void* __restrict__ A_,
                                               const ushort* __restrict__ Bp,
                                               const float* __restrict__ att_src,
                                               const float* __restrict__ att_dst,
                                               unsigned char* __restrict__ C8,
                                               float* __restrict__ a_src,
                                               float* __restrict__ a_dst,
                                               int M, int bid) {
  const int wave = threadIdx.x >> 6;
  const int lane = threadIdx.x & 63;
  const int strips = M / 16;
  const int strip = bid * 4 + wave;
  if (strip >= strips) return;
  const int r = lane & 15, kg = lane >> 4;
  const int row = strip * 16 + r;

  bf16x8 a[K / 32];
  if constexpr (AF32) {
    const float* Af = (const float*)A_;
    #pragma unroll
    for (int k0 = 0; k0 < K / 32; ++k0) {
      float4 f0 = *(const float4*)(Af + (size_t)row * K + k0 * 32 + kg * 8);
      float4 f1 = *(const float4*)(Af + (size_t)row * K + k0 * 32 + kg * 8 + 4);
      bf16x8 t;
      t[0] = (short)f2b(f0.x); t[1] = (short)f2b(f0.y);
      t[2] = (short)f2b(f0.z); t[3] = (short)f2b(f0.w);
      t[4] = (short)f2b(f1.x); t[5] = (short)f2b(f1.y);
      t[6] = (short)f2b(f1.z); t[7] = (short)f2b(f1.w);
      a[k0] = t;
    }
  } else {
    const ushort* Ab = (const ushort*)A_;
    #pragma unroll
    for (int k0 = 0; k0 < K / 32; ++k0)
      a[k0] = *(const bf16x8*)(Ab + (size_t)row * K + k0 * 32 + kg * 8);
  }

  float as_part[4] = {}, ad_part[4] = {};
  #pragma unroll 2
  for (int n0 = 0; n0 < N / 16; ++n0) {
    f32x4 acc = {0.f, 0.f, 0.f, 0.f};
    #pragma unroll
    for (int k0 = 0; k0 < K / 32; ++k0) {
      bf16x8 b = *(const bf16x8*)(Bp + ((size_t)(k0 * 4 + kg) * N + n0 * 16 + r) * 8);
      acc = __builtin_amdgcn_mfma_f32_16x16x32_bf16(a[k0], b, acc, 0, 0, 0);
    }
    float asv = att_src[n0 * 16 + r] * LOG2E;
    float adv = att_dst[n0 * 16 + r] * LOG2E;
    #pragma unroll
    for (int i = 0; i < 4; ++i) {
      as_part[i] = fmaf(acc[i], asv, as_part[i]);
      ad_part[i] = fmaf(acc[i], adv, ad_part[i]);
    }
    #pragma unroll
    for (int i = 0; i < 4; ++i) {
      int pk = __builtin_amdgcn_cvt_pk_fp8_f32(acc[i], acc[i], 0, false);
      C8[((size_t)strip * 16 + kg * 4 + i) * N + n0 * 16 + r] = (unsigned char)(pk & 0xFF);
    }
    if (((n0 + 1) * 16) % C == 0) {
      int h = (n0 * 16) / C;
      #pragma unroll
      for (int i = 0; i < 4; ++i) {
        float ts = as_part[i], td = ad_part[i];
        #pragma unroll
        for (int off = 1; off < 16; off <<= 1) {
          ts += __shfl_xor(ts, off);
          td += __shfl_xor(td, off);
        }
        if (r == i) {
          a_src[(size_t)(strip * 16 + kg * 4 + i) * H + h] = ts;
          a_dst[(size_t)(strip * 16 + kg * 4 + i) * H + h] = td;
        }
        as_part[i] = 0.f;
        ad_part[i] = 0.f;
      }
    }
  }
}

// ---------------- fused: gemm1 (blocks < GB) || edge rank pass (blocks >= GB)
template<int N, int K, int C, int H, bool AF32>
__global__ __launch_bounds__(256) void gemm_rank_k(const void* __restrict__ A_,
                                                   const ushort* __restrict__ Bp,
                                                   const float* __restrict__ att_src,
                                                   const float* __restrict__ att_dst,
                                                   unsigned char* __restrict__ C8,
                                                   float* __restrict__ a_src,
                                                   float* __restrict__ a_dst, int M,
                                                   const int* __restrict__ edst,
                                                   int* __restrict__ hist,
                                                   int* __restrict__ rank,
                                                   int E, int GB) {
  if ((int)blockIdx.x < GB) {
    gemm_attn_body<N, K, C, H, AF32>(A_, Bp, att_src, att_dst, C8, a_src, a_dst,
                                     M, blockIdx.x);
  } else {
    int base = ((blockIdx.x - GB) * 256 + threadIdx.x) * 8;
    #pragma unroll
    for (int u = 0; u < 8; ++u) {
      int e = base + u;
      if (e < E) rank[e] = atomicAdd(hist + edst[e], 1);
    }
  }
}

// ---------------- standalone gemm2 -------------------------------------------
template<int N, int K, int C, int H, bool AF32>
__global__ __launch_bounds__(256) void gemm_attn_k(const void* __restrict__ A_,
                                                   const ushort* __restrict__ Bp,
                                                   const float* __restrict__ att_src,
                                                   const float* __restrict__ att_dst,
                                                   unsigned char* __restrict__ C8,
                                                   float* __restrict__ a_src,
                                                   float* __restrict__ a_dst, int M) {
  gemm_attn_body<N, K, C, H, AF32>(A_, Bp, att_src, att_dst, C8, a_src, a_dst,
                                   M, blockIdx.x);
}

// ---------------- fused scan: hist -> rowptr (one 1024-thread block) ---------
__global__ __launch_bounds__(1024) void scan_fused_k(const int* __restrict__ hist,
                                                     int* __restrict__ rowptr,
                                                     int n, int total) {
  __shared__ int sums[1024];
  const int t = threadIdx.x;
  const int per = (n + 1023) / 1024;
  const int s0 = min(t * per, n);
  const int s1 = min(s0 + per, n);
  int s = 0;
  for (int i = s0; i < s1; ++i) s += hist[i];
  sums[t] = s;
  __syncthreads();
  for (int off = 1; off < 1024; off <<= 1) {
    int v = (t >= off) ? sums[t - off] : 0;
    __syncthreads();
    sums[t] += v;
    __syncthreads();
  }
  int run = sums[t] - s;     // exclusive prefix of this thread's range
  for (int i = s0; i < s1; ++i) { rowptr[i] = run; run += hist[i]; }
  if (t == 0) rowptr[n] = total;
}

// ---------------- fill: place edges (no atomics); zero pad tail --------------
__global__ __launch_bounds__(256) void fill_k(const int* __restrict__ esrc,
                                              const int* __restrict__ edst,
                                              const int* __restrict__ rowptr,
                                              const int* __restrict__ rank,
                                              int* __restrict__ csr_src,
                                              int E, int Epad) {
  int e = blockIdx.x * 256 + threadIdx.x;
  if (e < E) csr_src[rowptr[edst[e]] + rank[e]] = esrc[e];
  else if (e < Epad) csr_src[e] = 0;
}

// ---------------- layer-1 agg: wave per node, batched wave-parallel scores ---
template<int H, int C>
__global__ __launch_bounds__(256) void agg1_k(const int* __restrict__ rowptr,
                                              const int* __restrict__ csr,
                                              const float* __restrict__ a_src,
                                              const float* __restrict__ a_dst,
                                              const unsigned char* __restrict__ xl,
                                              const float* __restrict__ bias,
                                              ushort* __restrict__ out, int n) {
  constexpr int F = H * C;            // 256 bytes per fp8 row
  const int wid0 = (blockIdx.x * 256 + threadIdx.x) >> 6;
  if (wid0 >= n) return;
  const int wid = __builtin_amdgcn_readfirstlane(wid0);
  const int lane = threadIdx.x & 63;
  const int h = lane >> 4;            // gather head (4 ch/lane)
  const uint lofs = (uint)lane * 4;
  const int j4 = lane & 3;            // score head
  const int je = lane >> 2;           // score edge slot 0..15
  const int beg = rowptr[wid];
  const int end = rowptr[wid + 1];

  const float adh_s = a_dst[(uint)wid * 4 + j4];
  float vs_s = a_src[(uint)wid * 4 + j4] + adh_s;
  vs_s = fmaxf(vs_s, NEG_SLOPE * vs_s);

  float den = 1.f;
  float acc[4];
  {
    uint xs = *(const uint*)(xl + ((uint)wid * F + lofs));
    f32x2 lo = __builtin_amdgcn_cvt_pk_f32_fp8(xs, false);
    f32x2 hi = __builtin_amdgcn_cvt_pk_f32_fp8(xs, true);
    acc[0] = lo[0]; acc[1] = lo[1]; acc[2] = hi[0]; acc[3] = hi[1];
  }

  for (int j = beg; j < end; j += 16) {
    int sl = csr[j + je];                         // csr padded: safe
    float t = a_src[(uint)sl * 4 + j4] + adh_s;
    t = fmaxf(t, NEG_SLOPE * t);
    t = (j + je < end) ? t - vs_s : -1e30f;
    float pl = fexp2(t);
    uint xv[16];
    #pragma unroll
    for (int u = 0; u < 16; ++u) {
      int su = csr[j + u];
      xv[u] = *(const uint*)(xl + ((uint)su * F + lofs));
    }
    #pragma unroll
    for (int u = 0; u < 16; ++u) {
      float pu = __shfl(pl, u * 4 + h);
      den += pu;
      f32x2 lo = __builtin_amdgcn_cvt_pk_f32_fp8(xv[u], false);
      f32x2 hi = __builtin_amdgcn_cvt_pk_f32_fp8(xv[u], true);
      acc[0] = fmaf(pu, lo[0], acc[0]);
      acc[1] = fmaf(pu, lo[1], acc[1]);
      acc[2] = fmaf(pu, hi[0], acc[2]);
      acc[3] = fmaf(pu, hi[1], acc[3]);
    }
  }

  float inv = 1.f / (den + 1e-16f);
  float o[4];
  #pragma unroll
  for (int i = 0; i < 4; ++i)
    o[i] = fmaxf(fmaf(acc[i], inv, bias[lane * 4 + i]), 0.f);
  ushort4 ov = {f2b(o[0]), f2b(o[1]), f2b(o[2]), f2b(o[3])};
  *(ushort4*)(out + (size_t)wid * F + lane * 4) = ov;
}

// ---------------- layer-2 agg fused with mean-pool partials ------------------
// 2 nodes/wave, 8 nodes/block; rows reduced in LDS; <=2 graph-ids per block
// (batch sorted); atomics into 64-way replicated pp[rep][8][128].
__global__ __launch_bounds__(256) void agg2pool_k(const int* __restrict__ rowptr,
                                                  const int* __restrict__ csr,
                                                  const float* __restrict__ a_src,
                                                  const float* __restrict__ a_dst,
                                                  const unsigned char* __restrict__ xl,
                                                  const int* __restrict__ batch,
                                                  float* __restrict__ pp,
                                                  int n, int Emax) {
  const int pair = (blockIdx.x * 256 + threadIdx.x) >> 6;
  const int lane = threadIdx.x & 63;
  const int l32 = lane & 31;
  const int half = lane >> 5;
  int wid = pair * 2 + half;
  const bool act = wid < n;
  if (!act) wid = n - 1;
  const uint lofs = (uint)l32 * 4;
  const int beg = rowptr[wid];
  const int deg = rowptr[wid + 1] - beg;
  const int mdeg = max(deg, __shfl_xor(deg, 32));
  const float adh = a_dst[wid];

  float vs = a_src[wid] + adh;
  vs = fmaxf(vs, NEG_SLOPE * vs);
  float den = 1.f;
  float acc[4];
  {
    uint xs = *(const uint*)(xl + ((uint)wid * 128 + lofs));
    f32x2 lo = __builtin_amdgcn_cvt_pk_f32_fp8(xs, false);
    f32x2 hi = __builtin_amdgcn_cvt_pk_f32_fp8(xs, true);
    acc[0] = lo[0]; acc[1] = lo[1]; acc[2] = hi[0]; acc[3] = hi[1];
  }

  for (int j = 0; j < mdeg; j += 32) {
    int sl = csr[min(beg + j + l32, Emax)];
    float t = a_src[sl] + adh;
    t = fmaxf(t, NEG_SLOPE * t);
    t = (j + l32 < deg) ? t - vs : -1e30f;
    float pl = fexp2(t);
    #pragma unroll
    for (int g = 0; g < 2; ++g) {
      int su[16];
      uint xv[16];
      #pragma unroll
      for (int u = 0; u < 16; ++u) {
        su[u] = __shfl(sl, half * 32 + g * 16 + u);
        xv[u] = *(const uint*)(xl + ((uint)su[u] * 128 + lofs));
      }
      #pragma unroll
      for (int u = 0; u < 16; ++u) {
        float pu = __shfl(pl, half * 32 + g * 16 + u);
        den += pu;
        f32x2 lo = __builtin_amdgcn_cvt_pk_f32_fp8(xv[u], false);
        f32x2 hi = __builtin_amdgcn_cvt_pk_f32_fp8(xv[u], true);
        acc[0] = fmaf(pu, lo[0], acc[0]);
        acc[1] = fmaf(pu, lo[1], acc[1]);
        acc[2] = fmaf(pu, hi[0], acc[2]);
        acc[3] = fmaf(pu, hi[1], acc[3]);
      }
    }
  }

  // ---- block pool reduce (no out2 materialization) ----
  __shared__ float red[8][128];
  __shared__ int gids[8];
  const int rrow = (threadIdx.x >> 6) * 2 + half;   // 0..7
  float inv = act ? 1.f / (den + 1e-16f) : 0.f;     // inactive rows contribute 0
  float4 ov = {acc[0] * inv, acc[1] * inv, acc[2] * inv, acc[3] * inv};
  *(float4*)&red[rrow][l32 * 4] = ov;
  if (l32 == 0) gids[rrow] = act ? batch[wid] : -1;
  __syncthreads();
  if (threadIdx.x < 128) {
    const int ch = threadIdx.x;
    float* base = pp + (size_t)(blockIdx.x & (NREP - 1)) * 8 * 128;
    float sum = 0.f;
    int cur = gids[0];
    #pragma unroll
    for (int r = 0; r < 8; ++r) {
      int g = gids[r];
      if (g != cur) {
        if (cur >= 0) unsafeAtomicAdd(base + cur * 128 + ch, sum);
        sum = 0.f;
        cur = g;
      }
      if (g >= 0) sum += red[r][ch];
    }
    if (cur >= 0) unsafeAtomicAdd(base + cur * 128 + ch, sum);
  }
}

// ---------------- finalize: sum replicas, /cnt + bias ------------------------
__global__ __launch_bounds__(256) void finalize_k(const float* __restrict__ pp,
                                                  const int* __restrict__ batch,
                                                  const float* __restrict__ bias2,
                                                  float* __restrict__ out, int n) {
  int t = blockIdx.x * 256 + threadIdx.x;
  if (t >= 8 * 128) return;
  int g = t >> 7, c = t & 127;
  float s = 0.f;
  #pragma unroll 8
  for (int rep = 0; rep < NREP; ++rep) s += pp[rep * 8 * 128 + t];
  int lo = lbound(batch, n, g);
  int hi = lbound(batch, n, g + 1);
  float cnt = (float)(hi - lo);
  out[t] = s / fmaxf(cnt, 1.f) + bias2[c];
}

extern "C" void kernel_launch(void* const* d_in, const int* in_sizes, int n_in,
                              void* d_out, int out_size, void* d_ws, size_t ws_size,
                              hipStream_t stream) {
  const float* x        = (const float*)d_in[0];
  const int*   ei       = (const int*)d_in[1];
  const int*   batch    = (const int*)d_in[2];
  const float* W1       = (const float*)d_in[3];
  const float* att_src1 = (const float*)d_in[4];
  const float* att_dst1 = (const float*)d_in[5];
  const float* bias1    = (const float*)d_in[6];
  const float* W2       = (const float*)d_in[7];
  const float* att_src2 = (const float*)d_in[8];
  const float* att_dst2 = (const float*)d_in[9];
  const float* bias2    = (const float*)d_in[10];
  float* out = (float*)d_out;

  const int E  = in_sizes[1] / 2;
  const int NN = in_sizes[2];
  const int* esrc = ei;
  const int* edst = ei + E;
  const int PAD = 64;

  // ---- workspace layout ----
  char* w = (char*)d_ws;
  size_t woff = 0;
  auto walloc = [&](size_t bytes) -> char* {
    char* r = w + woff;
    woff += (bytes + 255) & ~(size_t)255;
    return r;
  };
  unsigned char* xl1 = (unsigned char*)walloc((size_t)NN * 256);  // fp8
  ushort* h1     = (ushort*)walloc((size_t)NN * 256 * 2);         // bf16
  unsigned char* xl2 = (unsigned char*)walloc((size_t)NN * 128);  // fp8
  float*  a_src1 = (float*)walloc((size_t)NN * 4 * 4);
  float*  a_dst1 = (float*)walloc((size_t)NN * 4 * 4);
  float*  a_src2 = (float*)walloc((size_t)NN * 4);
  float*  a_dst2 = (float*)walloc((size_t)NN * 4);
  int*    rowptr = (int*)walloc((size_t)(NN + 1) * 4);
  int*    hist   = (int*)walloc((size_t)NN * 4);
  int*    rank   = (int*)walloc((size_t)E * 4);
  int*    csrsrc = (int*)walloc((size_t)(E + PAD) * 4);
  ushort* Bp1    = (ushort*)walloc(128 * 256 * 2);
  ushort* Bp2    = (ushort*)walloc(256 * 128 * 2);
  float*  pp     = (float*)walloc((size_t)NREP * 8 * 128 * 4);

  dim3 blk(256);
  const int nbEp = (E + PAD + 255) / 256;
  const int nbN4 = (NN + 3) / 4;
  const int nbP  = ((NN + 1) / 2 + 3) / 4;         // agg2: 2 nodes/wave
  const int gblocks = (NN / 16 + 3) / 4;           // NN divisible by 16 (50000)
  const int rankBlocks = (E + 2047) / 2048;        // 8 edges/thread

  // 1) setup: pack weights, zero hist + pp
  setup_k<<<128, blk, 0, stream>>>(W1, Bp1, W2, Bp2, hist, pp, NN);

  // 2) gemm1 (f32 A -> fp8 xl1, attn coefs)  ||  rank pass (independent)
  gemm_rank_k<256, 128, 64, 4, true><<<gblocks + rankBlocks, blk, 0, stream>>>(
      x, Bp1, att_src1, att_dst1, xl1, a_src1, a_dst1, NN,
      edst, hist, rank, E, gblocks);

  // 3) fused scan: hist -> rowptr
  scan_fused_k<<<1, 1024, 0, stream>>>(hist, rowptr, NN, E);

  // 4) fill CSR (+ zero pad)
  fill_k<<<nbEp, blk, 0, stream>>>(esrc, edst, rowptr, rank, csrsrc, E, E + PAD);

  // 5) layer-1 aggregation
  agg1_k<4, 64><<<nbN4, blk, 0, stream>>>(
      rowptr, csrsrc, a_src1, a_dst1, xl1, bias1, h1, NN);

  // 6) gemm2 (bf16 A -> fp8 xl2, attn coefs)
  gemm_attn_k<128, 256, 128, 1, false><<<gblocks, blk, 0, stream>>>(
      h1, Bp2, att_src2, att_dst2, xl2, a_src2, a_dst2, NN);

  // 7) layer-2 aggregation fused with pool partials
  agg2pool_k<<<nbP, blk, 0, stream>>>(
      rowptr, csrsrc, a_src2, a_dst2, xl2, batch, pp, NN, E + PAD - 1);

  // 8) finalize
  finalize_k<<<4, blk, 0, stream>>>(pp, batch, bias2, out, NN);
}

// Round 13
// 162.273 us; speedup vs baseline: 1.4037x; 1.4037x over previous
//
#include <hip/hip_runtime.h>
#include <cstdint>
#include <cstddef>

#define NEG_SLOPE 0.2f
#define LOG2E 1.44269504088896f
#define NREP 64

typedef __attribute__((ext_vector_type(8))) short bf16x8;
typedef __attribute__((ext_vector_type(4))) float f32x4;
typedef __attribute__((ext_vector_type(2))) float f32x2;

__device__ __forceinline__ ushort f2b(float f) {   // fp32 -> bf16 RNE
  unsigned u = __float_as_uint(f);
  return (ushort)((u + 0x7FFFu + ((u >> 16) & 1)) >> 16);
}
__device__ __forceinline__ float fexp2(float x) {
#if __has_builtin(__builtin_amdgcn_exp2f)
  return __builtin_amdgcn_exp2f(x);
#else
  return __exp2f(x);
#endif
}
__device__ __forceinline__ int lbound(const int* __restrict__ a, int n, int key) {
  int lo = 0, hi = n;
  while (lo < hi) { int m = (lo + hi) >> 1; if (a[m] < key) lo = m + 1; else hi = m; }
  return lo;
}

// ---------------- setup: pack W1+W2 -> bf16 [K/8][N][8]; zero hist & pp ------
// grid: 128 blocks x 256 (i < 32768)
__global__ __launch_bounds__(256) void setup_k(const float* __restrict__ W1,
                                               ushort* __restrict__ Bp1,
                                               const float* __restrict__ W2,
                                               ushort* __restrict__ Bp2,
                                               int* __restrict__ hist,
                                               float* __restrict__ pp, int n) {
  int i = blockIdx.x * 256 + threadIdx.x;
  {
    int k = i >> 8, c = i & 255;                  // W1: K=128, N=256
    Bp1[(((size_t)(k >> 3) * 256 + c) << 3) + (k & 7)] = f2b(W1[i]);
  }
  {
    int k = i >> 7, c = i & 127;                  // W2: K=256, N=128
    Bp2[(((size_t)(k >> 3) * 128 + c) << 3) + (k & 7)] = f2b(W2[i]);
  }
  if (i < n) hist[i] = 0;
  int i2 = i + 32768;
  if (i2 < n) hist[i2] = 0;
  pp[i] = 0.f;                                    // pp = 64*8*128 = 65536
  pp[i + 32768] = 0.f;
}

// ---------------- shared GEMM+attn body (bf16 MFMA, fp8 C, exp2-domain attn) -
template<int N, int K, int C, int H, bool AF32>
__device__ __forceinline__ void gemm_attn_body(const void* __restrict__ A_,
                                               const ushort* __restrict__ Bp,
                                               const float* __restrict__ att_src,
                                               const float* __restrict__ att_dst,
                                               unsigned char* __restrict__ C8,
                                               float* __restrict__ a_src,
                                               float* __restrict__ a_dst,
                                               int M, int bid) {
  const int wave = threadIdx.x >> 6;
  const int lane = threadIdx.x & 63;
  const int strips = M / 16;
  const int strip = bid * 4 + wave;
  if (strip >= strips) return;
  const int r = lane & 15, kg = lane >> 4;
  const int row = strip * 16 + r;

  bf16x8 a[K / 32];
  if constexpr (AF32) {
    const float* Af = (const float*)A_;
    #pragma unroll
    for (int k0 = 0; k0 < K / 32; ++k0) {
      float4 f0 = *(const float4*)(Af + (size_t)row * K + k0 * 32 + kg * 8);
      float4 f1 = *(const float4*)(Af + (size_t)row * K + k0 * 32 + kg * 8 + 4);
      bf16x8 t;
      t[0] = (short)f2b(f0.x); t[1] = (short)f2b(f0.y);
      t[2] = (short)f2b(f0.z); t[3] = (short)f2b(f0.w);
      t[4] = (short)f2b(f1.x); t[5] = (short)f2b(f1.y);
      t[6] = (short)f2b(f1.z); t[7] = (short)f2b(f1.w);
      a[k0] = t;
    }
  } else {
    const ushort* Ab = (const ushort*)A_;
    #pragma unroll
    for (int k0 = 0; k0 < K / 32; ++k0)
      a[k0] = *(const bf16x8*)(Ab + (size_t)row * K + k0 * 32 + kg * 8);
  }

  float as_part[4] = {}, ad_part[4] = {};
  #pragma unroll 2
  for (int n0 = 0; n0 < N / 16; ++n0) {
    f32x4 acc = {0.f, 0.f, 0.f, 0.f};
    #pragma unroll
    for (int k0 = 0; k0 < K / 32; ++k0) {
      bf16x8 b = *(const bf16x8*)(Bp + ((size_t)(k0 * 4 + kg) * N + n0 * 16 + r) * 8);
      acc = __builtin_amdgcn_mfma_f32_16x16x32_bf16(a[k0], b, acc, 0, 0, 0);
    }
    float asv = att_src[n0 * 16 + r] * LOG2E;
    float adv = att_dst[n0 * 16 + r] * LOG2E;
    #pragma unroll
    for (int i = 0; i < 4; ++i) {
      as_part[i] = fmaf(acc[i], asv, as_part[i]);
      ad_part[i] = fmaf(acc[i], adv, ad_part[i]);
    }
    #pragma unroll
    for (int i = 0; i < 4; ++i) {
      int pk = __builtin_amdgcn_cvt_pk_fp8_f32(acc[i], acc[i], 0, false);
      C8[((size_t)strip * 16 + kg * 4 + i) * N + n0 * 16 + r] = (unsigned char)(pk & 0xFF);
    }
    if (((n0 + 1) * 16) % C == 0) {
      int h = (n0 * 16) / C;
      #pragma unroll
      for (int i = 0; i < 4; ++i) {
        float ts = as_part[i], td = ad_part[i];
        #pragma unroll
        for (int off = 1; off < 16; off <<= 1) {
          ts += __shfl_xor(ts, off);
          td += __shfl_xor(td, off);
        }
        if (r == i) {
          a_src[(size_t)(strip * 16 + kg * 4 + i) * H + h] = ts;
          a_dst[(size_t)(strip * 16 + kg * 4 + i) * H + h] = td;
        }
        as_part[i] = 0.f;
        ad_part[i] = 0.f;
      }
    }
  }
}

// ---------------- fused: gemm1 (blocks < GB) || edge rank pass (blocks >= GB)
template<int N, int K, int C, int H, bool AF32>
__global__ __launch_bounds__(256) void gemm_rank_k(const void* __restrict__ A_,
                                                   const ushort* __restrict__ Bp,
                                                   const float* __restrict__ att_src,
                                                   const float* __restrict__ att_dst,
                                                   unsigned char* __restrict__ C8,
                                                   float* __restrict__ a_src,
                                                   float* __restrict__ a_dst, int M,
                                                   const int* __restrict__ edst,
                                                   int* __restrict__ hist,
                                                   int* __restrict__ rank,
                                                   int E, int GB) {
  if ((int)blockIdx.x < GB) {
    gemm_attn_body<N, K, C, H, AF32>(A_, Bp, att_src, att_dst, C8, a_src, a_dst,
                                     M, blockIdx.x);
  } else {
    int base = ((blockIdx.x - GB) * 256 + threadIdx.x) * 8;
    #pragma unroll
    for (int u = 0; u < 8; ++u) {
      int e = base + u;
      if (e < E) rank[e] = atomicAdd(hist + edst[e], 1);
    }
  }
}

// ---------------- standalone gemm2 -------------------------------------------
template<int N, int K, int C, int H, bool AF32>
__global__ __launch_bounds__(256) void gemm_attn_k(const void* __restrict__ A_,
                                                   const ushort* __restrict__ Bp,
                                                   const float* __restrict__ att_src,
                                                   const float* __restrict__ att_dst,
                                                   unsigned char* __restrict__ C8,
                                                   float* __restrict__ a_src,
                                                   float* __restrict__ a_dst, int M) {
  gemm_attn_body<N, K, C, H, AF32>(A_, Bp, att_src, att_dst, C8, a_src, a_dst,
                                   M, blockIdx.x);
}

// ---------------- multi-block scan: per-1024-chunk (int4 + LDS) --------------
__global__ __launch_bounds__(256) void scan1_k(const int* __restrict__ hist,
                                               int* __restrict__ excl,
                                               int* __restrict__ chunksum, int n) {
  __shared__ int sums[256];
  int base = blockIdx.x * 1024 + threadIdx.x * 4;
  int4 v = {0, 0, 0, 0};
  if (base + 3 < n) v = *(const int4*)(hist + base);
  else {
    if (base < n)     v.x = hist[base];
    if (base + 1 < n) v.y = hist[base + 1];
    if (base + 2 < n) v.z = hist[base + 2];
    if (base + 3 < n) v.w = hist[base + 3];
  }
  int s = v.x + v.y + v.z + v.w;
  sums[threadIdx.x] = s;
  __syncthreads();
  for (int off = 1; off < 256; off <<= 1) {
    int t = (threadIdx.x >= (unsigned)off) ? sums[threadIdx.x - off] : 0;
    __syncthreads();
    sums[threadIdx.x] += t;
    __syncthreads();
  }
  if (threadIdx.x == 255) chunksum[blockIdx.x] = sums[255];
  int e0 = sums[threadIdx.x] - s;
  int e1 = e0 + v.x, e2 = e1 + v.y, e3 = e2 + v.z;
  if (base + 3 < n) {
    int4 o = {e0, e1, e2, e3};
    *(int4*)(excl + base) = o;
  } else {
    if (base < n)     excl[base] = e0;
    if (base + 1 < n) excl[base + 1] = e1;
    if (base + 2 < n) excl[base + 2] = e2;
    if (base + 3 < n) excl[base + 3] = e3;
  }
}

__global__ void scan2_k(const int* __restrict__ chunksum,
                        int* __restrict__ chunkoff, int nchunks) {
  if (threadIdx.x == 0) {
    int run = 0;
    for (int c = 0; c < nchunks; ++c) { chunkoff[c] = run; run += chunksum[c]; }
  }
}

__global__ __launch_bounds__(256) void addoff_k(int* __restrict__ rowptr,
                                                const int* __restrict__ chunkoff,
                                                int n, int total) {
  int i = blockIdx.x * 256 + threadIdx.x;
  if (i == 0) rowptr[n] = total;
  if (i >= n) return;
  rowptr[i] += chunkoff[i >> 10];
}

// ---------------- fill: place edges (no atomics); zero pad tail --------------
__global__ __launch_bounds__(256) void fill_k(const int* __restrict__ esrc,
                                              const int* __restrict__ edst,
                                              const int* __restrict__ rowptr,
                                              const int* __restrict__ rank,
                                              int* __restrict__ csr_src,
                                              int E, int Epad) {
  int e = blockIdx.x * 256 + threadIdx.x;
  if (e < E) csr_src[rowptr[edst[e]] + rank[e]] = esrc[e];
  else if (e < Epad) csr_src[e] = 0;
}

// ---------------- layer-1 agg: wave per node, batched wave-parallel scores ---
template<int H, int C>
__global__ __launch_bounds__(256) void agg1_k(const int* __restrict__ rowptr,
                                              const int* __restrict__ csr,
                                              const float* __restrict__ a_src,
                                              const float* __restrict__ a_dst,
                                              const unsigned char* __restrict__ xl,
                                              const float* __restrict__ bias,
                                              ushort* __restrict__ out, int n) {
  constexpr int F = H * C;            // 256 bytes per fp8 row
  const int wid0 = (blockIdx.x * 256 + threadIdx.x) >> 6;
  if (wid0 >= n) return;
  const int wid = __builtin_amdgcn_readfirstlane(wid0);
  const int lane = threadIdx.x & 63;
  const int h = lane >> 4;            // gather head (4 ch/lane)
  const uint lofs = (uint)lane * 4;
  const int j4 = lane & 3;            // score head
  const int je = lane >> 2;           // score edge slot 0..15
  const int beg = rowptr[wid];
  const int end = rowptr[wid + 1];

  const float adh_s = a_dst[(uint)wid * 4 + j4];
  float vs_s = a_src[(uint)wid * 4 + j4] + adh_s;
  vs_s = fmaxf(vs_s, NEG_SLOPE * vs_s);

  float den = 1.f;
  float acc[4];
  {
    uint xs = *(const uint*)(xl + ((uint)wid * F + lofs));
    f32x2 lo = __builtin_amdgcn_cvt_pk_f32_fp8(xs, false);
    f32x2 hi = __builtin_amdgcn_cvt_pk_f32_fp8(xs, true);
    acc[0] = lo[0]; acc[1] = lo[1]; acc[2] = hi[0]; acc[3] = hi[1];
  }

  for (int j = beg; j < end; j += 16) {
    int sl = csr[j + je];                         // csr padded: safe
    float t = a_src[(uint)sl * 4 + j4] + adh_s;
    t = fmaxf(t, NEG_SLOPE * t);
    t = (j + je < end) ? t - vs_s : -1e30f;
    float pl = fexp2(t);
    uint xv[16];
    #pragma unroll
    for (int u = 0; u < 16; ++u) {
      int su = csr[j + u];
      xv[u] = *(const uint*)(xl + ((uint)su * F + lofs));
    }
    #pragma unroll
    for (int u = 0; u < 16; ++u) {
      float pu = __shfl(pl, u * 4 + h);
      den += pu;
      f32x2 lo = __builtin_amdgcn_cvt_pk_f32_fp8(xv[u], false);
      f32x2 hi = __builtin_amdgcn_cvt_pk_f32_fp8(xv[u], true);
      acc[0] = fmaf(pu, lo[0], acc[0]);
      acc[1] = fmaf(pu, lo[1], acc[1]);
      acc[2] = fmaf(pu, hi[0], acc[2]);
      acc[3] = fmaf(pu, hi[1], acc[3]);
    }
  }

  float inv = 1.f / (den + 1e-16f);
  float o[4];
  #pragma unroll
  for (int i = 0; i < 4; ++i)
    o[i] = fmaxf(fmaf(acc[i], inv, bias[lane * 4 + i]), 0.f);
  ushort4 ov = {f2b(o[0]), f2b(o[1]), f2b(o[2]), f2b(o[3])};
  *(ushort4*)(out + (size_t)wid * F + lane * 4) = ov;
}

// ---------------- layer-2 agg fused with mean-pool partials ------------------
__global__ __launch_bounds__(256) void agg2pool_k(const int* __restrict__ rowptr,
                                                  const int* __restrict__ csr,
                                                  const float* __restrict__ a_src,
                                                  const float* __restrict__ a_dst,
                                                  const unsigned char* __restrict__ xl,
                                                  const int* __restrict__ batch,
                                                  float* __restrict__ pp,
                                                  int n, int Emax) {
  const int pair = (blockIdx.x * 256 + threadIdx.x) >> 6;
  const int lane = threadIdx.x & 63;
  const int l32 = lane & 31;
  const int half = lane >> 5;
  int wid = pair * 2 + half;
  const bool act = wid < n;
  if (!act) wid = n - 1;
  const uint lofs = (uint)l32 * 4;
  const int beg = rowptr[wid];
  const int deg = rowptr[wid + 1] - beg;
  const int mdeg = max(deg, __shfl_xor(deg, 32));
  const float adh = a_dst[wid];

  float vs = a_src[wid] + adh;
  vs = fmaxf(vs, NEG_SLOPE * vs);
  float den = 1.f;
  float acc[4];
  {
    uint xs = *(const uint*)(xl + ((uint)wid * 128 + lofs));
    f32x2 lo = __builtin_amdgcn_cvt_pk_f32_fp8(xs, false);
    f32x2 hi = __builtin_amdgcn_cvt_pk_f32_fp8(xs, true);
    acc[0] = lo[0]; acc[1] = lo[1]; acc[2] = hi[0]; acc[3] = hi[1];
  }

  for (int j = 0; j < mdeg; j += 32) {
    int sl = csr[min(beg + j + l32, Emax)];
    float t = a_src[sl] + adh;
    t = fmaxf(t, NEG_SLOPE * t);
    t = (j + l32 < deg) ? t - vs : -1e30f;
    float pl = fexp2(t);
    #pragma unroll
    for (int g = 0; g < 2; ++g) {
      int su[16];
      uint xv[16];
      #pragma unroll
      for (int u = 0; u < 16; ++u) {
        su[u] = __shfl(sl, half * 32 + g * 16 + u);
        xv[u] = *(const uint*)(xl + ((uint)su[u] * 128 + lofs));
      }
      #pragma unroll
      for (int u = 0; u < 16; ++u) {
        float pu = __shfl(pl, half * 32 + g * 16 + u);
        den += pu;
        f32x2 lo = __builtin_amdgcn_cvt_pk_f32_fp8(xv[u], false);
        f32x2 hi = __builtin_amdgcn_cvt_pk_f32_fp8(xv[u], true);
        acc[0] = fmaf(pu, lo[0], acc[0]);
        acc[1] = fmaf(pu, lo[1], acc[1]);
        acc[2] = fmaf(pu, hi[0], acc[2]);
        acc[3] = fmaf(pu, hi[1], acc[3]);
      }
    }
  }

  // ---- block pool reduce (no out2 materialization) ----
  __shared__ float red[8][128];
  __shared__ int gids[8];
  const int rrow = (threadIdx.x >> 6) * 2 + half;   // 0..7
  float inv = act ? 1.f / (den + 1e-16f) : 0.f;     // inactive rows contribute 0
  float4 ov = {acc[0] * inv, acc[1] * inv, acc[2] * inv, acc[3] * inv};
  *(float4*)&red[rrow][l32 * 4] = ov;
  if (l32 == 0) gids[rrow] = act ? batch[wid] : -1;
  __syncthreads();
  if (threadIdx.x < 128) {
    const int ch = threadIdx.x;
    float* base = pp + (size_t)(blockIdx.x & (NREP - 1)) * 8 * 128;
    float sum = 0.f;
    int cur = gids[0];
    #pragma unroll
    for (int r = 0; r < 8; ++r) {
      int g = gids[r];
      if (g != cur) {
        if (cur >= 0) unsafeAtomicAdd(base + cur * 128 + ch, sum);
        sum = 0.f;
        cur = g;
      }
      if (g >= 0) sum += red[r][ch];
    }
    if (cur >= 0) unsafeAtomicAdd(base + cur * 128 + ch, sum);
  }
}

// ---------------- finalize: sum replicas, /cnt + bias ------------------------
__global__ __launch_bounds__(256) void finalize_k(const float* __restrict__ pp,
                                                  const int* __restrict__ batch,
                                                  const float* __restrict__ bias2,
                                                  float* __restrict__ out, int n) {
  int t = blockIdx.x * 256 + threadIdx.x;
  if (t >= 8 * 128) return;
  int g = t >> 7, c = t & 127;
  float s = 0.f;
  #pragma unroll 8
  for (int rep = 0; rep < NREP; ++rep) s += pp[rep * 8 * 128 + t];
  int lo = lbound(batch, n, g);
  int hi = lbound(batch, n, g + 1);
  float cnt = (float)(hi - lo);
  out[t] = s / fmaxf(cnt, 1.f) + bias2[c];
}

extern "C" void kernel_launch(void* const* d_in, const int* in_sizes, int n_in,
                              void* d_out, int out_size, void* d_ws, size_t ws_size,
                              hipStream_t stream) {
  const float* x        = (const float*)d_in[0];
  const int*   ei       = (const int*)d_in[1];
  const int*   batch    = (const int*)d_in[2];
  const float* W1       = (const float*)d_in[3];
  const float* att_src1 = (const float*)d_in[4];
  const float* att_dst1 = (const float*)d_in[5];
  const float* bias1    = (const float*)d_in[6];
  const float* W2       = (const float*)d_in[7];
  const float* att_src2 = (const float*)d_in[8];
  const float* att_dst2 = (const float*)d_in[9];
  const float* bias2    = (const float*)d_in[10];
  float* out = (float*)d_out;

  const int E  = in_sizes[1] / 2;
  const int NN = in_sizes[2];
  const int* esrc = ei;
  const int* edst = ei + E;
  const int PAD = 64;

  // ---- workspace layout ----
  char* w = (char*)d_ws;
  size_t woff = 0;
  auto walloc = [&](size_t bytes) -> char* {
    char* r = w + woff;
    woff += (bytes + 255) & ~(size_t)255;
    return r;
  };
  unsigned char* xl1 = (unsigned char*)walloc((size_t)NN * 256);  // fp8
  ushort* h1     = (ushort*)walloc((size_t)NN * 256 * 2);         // bf16
  unsigned char* xl2 = (unsigned char*)walloc((size_t)NN * 128);  // fp8
  float*  a_src1 = (float*)walloc((size_t)NN * 4 * 4);
  float*  a_dst1 = (float*)walloc((size_t)NN * 4 * 4);
  float*  a_src2 = (float*)walloc((size_t)NN * 4);
  float*  a_dst2 = (float*)walloc((size_t)NN * 4);
  int*    rowptr = (int*)walloc((size_t)(NN + 1) * 4);
  int*    hist   = (int*)walloc((size_t)NN * 4);
  int*    rank   = (int*)walloc((size_t)E * 4);
  int*    csrsrc = (int*)walloc((size_t)(E + PAD) * 4);
  ushort* Bp1    = (ushort*)walloc(128 * 256 * 2);
  ushort* Bp2    = (ushort*)walloc(256 * 128 * 2);
  int*    chunks = (int*)walloc(256 * 4);
  int*    chunko = (int*)walloc(256 * 4);
  float*  pp     = (float*)walloc((size_t)NREP * 8 * 128 * 4);

  dim3 blk(256);
  const int nbEp = (E + PAD + 255) / 256;
  const int nbN4 = (NN + 3) / 4;
  const int nbP  = ((NN + 1) / 2 + 3) / 4;         // agg2: 2 nodes/wave
  const int gblocks = (NN / 16 + 3) / 4;           // NN divisible by 16 (50000)
  const int rankBlocks = (E + 2047) / 2048;        // 8 edges/thread
  const int nchunks = (NN + 1023) / 1024;

  // 1) setup: pack weights, zero hist + pp
  setup_k<<<128, blk, 0, stream>>>(W1, Bp1, W2, Bp2, hist, pp, NN);

  // 2) gemm1 (f32 A -> fp8 xl1, attn coefs)  ||  rank pass (independent)
  gemm_rank_k<256, 128, 64, 4, true><<<gblocks + rankBlocks, blk, 0, stream>>>(
      x, Bp1, att_src1, att_dst1, xl1, a_src1, a_dst1, NN,
      edst, hist, rank, E, gblocks);

  // 3-5) multi-block scan: hist -> rowptr
  scan1_k<<<nchunks, blk, 0, stream>>>(hist, rowptr, chunks, NN);
  scan2_k<<<1, 64, 0, stream>>>(chunks, chunko, nchunks);
  addoff_k<<<(NN + 255) / 256, blk, 0, stream>>>(rowptr, chunko, NN, E);

  // 6) fill CSR (+ zero pad)
  fill_k<<<nbEp, blk, 0, stream>>>(esrc, edst, rowptr, rank, csrsrc, E, E + PAD);

  // 7) layer-1 aggregation
  agg1_k<4, 64><<<nbN4, blk, 0, stream>>>(
      rowptr, csrsrc, a_src1, a_dst1, xl1, bias1, h1, NN);

  // 8) gemm2 (bf16 A -> fp8 xl2, attn coefs)
  gemm_attn_k<128, 256, 128, 1, false><<<gblocks, blk, 0, stream>>>(
      h1, Bp2, att_src2, att_dst2, xl2, a_src2, a_dst2, NN);

  // 9) layer-2 aggregation fused with pool partials
  agg2pool_k<<<nbP, blk, 0, stream>>>(
      rowptr, csrsrc, a_src2, a_dst2, xl2, batch, pp, NN, E + PAD - 1);

  // 10) finalize
  finalize_k<<<4, blk, 0, stream>>>(pp, batch, bias2, out, NN);
}